// Round 2
// baseline (502.115 us; speedup 1.0000x reference)
//
#include <hip/hip_runtime.h>
#include <hip/hip_bf16.h>
#include <cstdint>

#define DI __device__ __forceinline__

typedef short bf16x8 __attribute__((ext_vector_type(8)));
typedef float f32x4 __attribute__((ext_vector_type(4)));
typedef unsigned short u16;
typedef unsigned short u16x4 __attribute__((ext_vector_type(4)));
typedef unsigned short u16x8 __attribute__((ext_vector_type(8)));

static constexpr int NV = 10, NE = 90, TT = 64;
static constexpr int R1 = 20480;   // 32*10*64 node rows
static constexpr int R2 = 184320;  // 32*90*64 edge rows

DI float bf2f(u16 u) { union { unsigned int i; float f; } x; x.i = ((unsigned int)u) << 16; return x.f; }
DI u16 f2bf(float f) { unsigned int u = __float_as_uint(f); return (u16)((u + 0x7FFF + ((u >> 16) & 1)) >> 16); }
DI float elu(float v) { return v > 0.f ? v : __expf(v) - 1.f; }

#define GLL(srcp, dstp) __builtin_amdgcn_global_load_lds( \
    (const __attribute__((address_space(1))) unsigned int*)(srcp), \
    (__attribute__((address_space(3))) unsigned int*)(dstp), 16, 0, 0)

// -------------------- weight convert + transpose: [K,N] f32 -> [N,K] bf16 ---
__global__ __launch_bounds__(256) void transpose_w(const float* __restrict__ src,
                                                   u16* __restrict__ dst, int K, int N) {
    int idx = blockIdx.x * 256 + threadIdx.x;
    if (idx >= K * N) return;
    int k = idx / N, n = idx - k * N;
    dst[(size_t)n * K + k] = f2bf(src[idx]);
}

__global__ void zero_stats(float* p, int n) {
    int i = blockIdx.x * 256 + threadIdx.x;
    if (i < n) p[i] = 0.f;
}

// fold BN1 affine scale into w2a (transposed), shift into bias
__global__ __launch_bounds__(256) void fold_w2a(const float* __restrict__ w2a,
                                                const float* __restrict__ scsh1,
                                                u16* __restrict__ w2aT) {
    int k = blockIdx.x, n = threadIdx.x;
    w2aT[(size_t)n * 512 + k] = f2bf(scsh1[k & 255] * w2a[k * 256 + n]);
}
__global__ __launch_bounds__(256) void fold_b2a(const float* __restrict__ w2a,
                                                const float* __restrict__ scsh1,
                                                const float* __restrict__ b2a,
                                                float* __restrict__ b2aF) {
    int n = threadIdx.x;
    float s = b2a[n];
    for (int k = 0; k < 512; ++k) s += scsh1[256 + (k & 255)] * w2a[k * 256 + n];
    b2aF[n] = s;
}

__global__ void stats_final(const float* __restrict__ sums, const float* __restrict__ g,
                            const float* __restrict__ be, float invR, float* __restrict__ scsh) {
    int c = threadIdx.x;
    float mu = sums[c] * invR;
    float var = sums[256 + c] * invR - mu * mu;
    float rs = rsqrtf(var + 1e-5f);
    float sc = g[c] * rs;
    scsh[c] = sc;
    scsh[256 + c] = be[c] - mu * sc;
}

// ============================================================================
// Unified MFMA GEMM, M-tile=64, N=256 (full), BK=64, 4 waves, swizzled LDS.
// Operand swap: mfma(Wfrag, Afrag, acc) -> D[n][m], lane&15 = m, regs = 4
// consecutive n  => packed b64 H1 writes + coalesced LDS-transpose stores.
// STG: 0 direct gload_lds | 1 node2edge gather gload_lds | 2 compute mlp1-fc1
//      | 3 affine3+relu reg-staging
// MODE: 0 single gemm, elu+stats+store | 1 fused two gemms, elu+stats+store
//       | 2 head: relu(.+bo1) dot wo2 -> f32 out
// ============================================================================
template <int STG, int MODE>
__global__ __launch_bounds__(256, 2) void mm(
    const u16* __restrict__ A, int K,
    const u16* __restrict__ W1, const float* __restrict__ bias1,
    const u16* __restrict__ W2, const float* __restrict__ bias2,
    const float* __restrict__ aux0, const float* __restrict__ aux1,
    const float* __restrict__ aux2,
    u16* __restrict__ outB, float* __restrict__ stats, float* __restrict__ fout)
{
    __shared__ u16 As[64 * 64];    // 8 KB
    __shared__ u16 Bs[256 * 64];   // 32 KB
    __shared__ u16 H1[64 * 256];   // 32 KB (fc1 mid / out staging / head rowacc)

    const int tid = threadIdx.x;
    const int wid = tid >> 6;
    const int lane = tid & 63;
    const int g = lane >> 4;
    const int lr = lane & 15;
    const int m0 = blockIdx.x * 64;
    const int scol = ((tid & 7) ^ ((tid >> 3) & 7)) * 8;  // swizzled k-offset (staging)

    size_t ab0 = 0, ab1 = 0, sb0 = 0, sb1 = 0, rb0 = 0, rb1 = 0;
    if constexpr (STG == 1) {
        {
            int m = m0 + (tid >> 3);
            int t = m & 63, be = m >> 6, e = be % NE, b = be / NE;
            int s = e / 9, kk = e - s * 9, r = kk + (kk >= s ? 1 : 0);
            sb0 = ((size_t)((b * NV + s) * TT + t)) * 256;
            rb0 = ((size_t)((b * NV + r) * TT + t)) * 256;
        }
        {
            int m = m0 + 32 + (tid >> 3);
            int t = m & 63, be = m >> 6, e = be % NE, b = be / NE;
            int s = e / 9, kk = e - s * 9, r = kk + (kk >= s ? 1 : 0);
            sb1 = ((size_t)((b * NV + s) * TT + t)) * 256;
            rb1 = ((size_t)((b * NV + r) * TT + t)) * 256;
        }
    } else if constexpr (STG == 0) {
        ab0 = (size_t)(m0 + (tid >> 3)) * K;
        ab1 = (size_t)(m0 + 32 + (tid >> 3)) * K;
    }

    f32x4 acc[4][4];
#pragma unroll
    for (int i = 0; i < 4; ++i)
#pragma unroll
        for (int j = 0; j < 4; ++j) acc[i][j] = (f32x4)0.f;

    // ---------------- GEMM 1 ----------------
    for (int k0 = 0; k0 < K; k0 += 64) {
        if constexpr (STG == 0) {
            GLL(A + ab0 + k0 + scol, As + (wid * 64) * 8);
            GLL(A + ab1 + k0 + scol, As + (256 + wid * 64) * 8);
        } else if constexpr (STG == 1) {
            const u16* s0 = A + (k0 < 256 ? sb0 : rb0) + (k0 & 255) + scol;
            const u16* s1 = A + (k0 < 256 ? sb1 : rb1) + (k0 & 255) + scol;
            GLL(s0, As + (wid * 64) * 8);
            GLL(s1, As + (256 + wid * 64) * 8);
        } else if constexpr (STG == 2) {
#pragma unroll
            for (int q = 0; q < 2; ++q) {
                int ar = q * 32 + (tid >> 3);
                int m = m0 + ar;
                int b_ = m / (NV * TT), v_ = (m >> 6) % NV, t_ = m & 63;
                const float* xp = aux0 + ((size_t)((b_ * TT + t_) * NV + v_)) * 4;
                float x0 = xp[0], x1 = xp[1], x2 = xp[2], x3 = xp[3];
                u16x8 pk;
#pragma unroll
                for (int e = 0; e < 8; ++e) {
                    int ch = k0 + (tid & 7) * 8 + e;
                    float a_ = aux2[ch] + x0 * aux1[ch] + x1 * aux1[256 + ch] +
                               x2 * aux1[512 + ch] + x3 * aux1[768 + ch];
                    pk[e] = f2bf(elu(a_));
                }
                *(u16x8*)&As[ar * 64 + scol] = pk;
            }
        } else {  // STG == 3: affine(scsh3) + relu
#pragma unroll
            for (int q = 0; q < 2; ++q) {
                int ar = q * 32 + (tid >> 3);
                u16x8 vin = *(const u16x8*)(A + (size_t)(m0 + ar) * 256 + k0 + (tid & 7) * 8);
                u16x8 pk;
#pragma unroll
                for (int e = 0; e < 8; ++e) {
                    int ch = k0 + (tid & 7) * 8 + e;
                    float f = bf2f(vin[e]) * aux0[ch] + aux0[256 + ch];
                    pk[e] = f2bf(f > 0.f ? f : 0.f);
                }
                *(u16x8*)&As[ar * 64 + scol] = pk;
            }
        }
#pragma unroll
        for (int q = 0; q < 8; ++q) {
            int br = q * 32 + (tid >> 3);
            GLL(W1 + (size_t)br * K + k0 + scol, Bs + (q * 256 + wid * 64) * 8);
        }
        __syncthreads();
#pragma unroll
        for (int s = 0; s < 2; ++s) {
            bf16x8 av[4], bv[4];
#pragma unroll
            for (int i = 0; i < 4; ++i) {
                int mr = i * 16 + lr;
                int cl = s * 4 + g;
                av[i] = *(const bf16x8*)&As[mr * 64 + (cl ^ (mr & 7)) * 8];
            }
#pragma unroll
            for (int j = 0; j < 4; ++j) {
                int nr = wid * 64 + j * 16 + lr;
                int cl = s * 4 + g;
                bv[j] = *(const bf16x8*)&Bs[nr * 64 + (cl ^ (nr & 7)) * 8];
            }
#pragma unroll
            for (int i = 0; i < 4; ++i)
#pragma unroll
                for (int j = 0; j < 4; ++j)
                    acc[i][j] = __builtin_amdgcn_mfma_f32_16x16x32_bf16(bv[j], av[i], acc[i][j], 0, 0, 0);
        }
        __syncthreads();
    }

    // ---------------- fused GEMM 2 ----------------
    if constexpr (MODE == 1) {
        // fc1 epilogue: bias+elu -> H1 (swizzled b64 writes)
#pragma unroll
        for (int j = 0; j < 4; ++j) {
            int n4 = wid * 64 + j * 16 + g * 4;
            float b0 = bias1[n4], b1_ = bias1[n4 + 1], b2_ = bias1[n4 + 2], b3_ = bias1[n4 + 3];
#pragma unroll
            for (int i = 0; i < 4; ++i) {
                int m = i * 16 + lr;
                u16x4 pk;
                pk[0] = f2bf(elu(acc[i][j][0] + b0));
                pk[1] = f2bf(elu(acc[i][j][1] + b1_));
                pk[2] = f2bf(elu(acc[i][j][2] + b2_));
                pk[3] = f2bf(elu(acc[i][j][3] + b3_));
                *(u16x4*)&H1[m * 256 + (((n4 >> 3) ^ (m & 7))) * 8 + (n4 & 7)] = pk;
            }
        }
        __syncthreads();
#pragma unroll
        for (int i = 0; i < 4; ++i)
#pragma unroll
            for (int j = 0; j < 4; ++j) acc[i][j] = (f32x4)0.f;
        for (int k0 = 0; k0 < 256; k0 += 64) {
#pragma unroll
            for (int q = 0; q < 8; ++q) {
                int br = q * 32 + (tid >> 3);
                GLL(W2 + (size_t)br * 256 + k0 + scol, Bs + (q * 256 + wid * 64) * 8);
            }
            __syncthreads();
#pragma unroll
            for (int s = 0; s < 2; ++s) {
                bf16x8 av[4], bv[4];
#pragma unroll
                for (int i = 0; i < 4; ++i) {
                    int mr = i * 16 + lr;
                    int cl = (k0 >> 3) + s * 4 + g;
                    av[i] = *(const bf16x8*)&H1[mr * 256 + (cl ^ (mr & 7)) * 8];
                }
#pragma unroll
                for (int j = 0; j < 4; ++j) {
                    int nr = wid * 64 + j * 16 + lr;
                    int cl = s * 4 + g;
                    bv[j] = *(const bf16x8*)&Bs[nr * 64 + (cl ^ (nr & 7)) * 8];
                }
#pragma unroll
                for (int i = 0; i < 4; ++i)
#pragma unroll
                    for (int j = 0; j < 4; ++j)
                        acc[i][j] = __builtin_amdgcn_mfma_f32_16x16x32_bf16(bv[j], av[i], acc[i][j], 0, 0, 0);
            }
            __syncthreads();
        }
    }

    // ---------------- final epilogue ----------------
    if constexpr (MODE <= 1) {
        const float* bf = (MODE == 0) ? bias1 : bias2;
        float sv[4][4], qv[4][4];
#pragma unroll
        for (int j = 0; j < 4; ++j)
#pragma unroll
            for (int r = 0; r < 4; ++r) { sv[j][r] = 0.f; qv[j][r] = 0.f; }
#pragma unroll
        for (int j = 0; j < 4; ++j) {
            int n4 = wid * 64 + j * 16 + g * 4;
            float bb0 = bf[n4], bb1 = bf[n4 + 1], bb2 = bf[n4 + 2], bb3 = bf[n4 + 3];
#pragma unroll
            for (int i = 0; i < 4; ++i) {
                int m = i * 16 + lr;
                float v0 = elu(acc[i][j][0] + bb0);
                float v1 = elu(acc[i][j][1] + bb1);
                float v2 = elu(acc[i][j][2] + bb2);
                float v3 = elu(acc[i][j][3] + bb3);
                sv[j][0] += v0; qv[j][0] += v0 * v0;
                sv[j][1] += v1; qv[j][1] += v1 * v1;
                sv[j][2] += v2; qv[j][2] += v2 * v2;
                sv[j][3] += v3; qv[j][3] += v3 * v3;
                u16x4 pk;
                pk[0] = f2bf(v0); pk[1] = f2bf(v1); pk[2] = f2bf(v2); pk[3] = f2bf(v3);
                *(u16x4*)&H1[m * 256 + (((n4 >> 3) ^ (m & 7))) * 8 + (n4 & 7)] = pk;
            }
        }
#pragma unroll
        for (int j = 0; j < 4; ++j)
#pragma unroll
            for (int r = 0; r < 4; ++r) {
                float s = sv[j][r], q_ = qv[j][r];
                s += __shfl_xor(s, 1);  q_ += __shfl_xor(q_, 1);
                s += __shfl_xor(s, 2);  q_ += __shfl_xor(q_, 2);
                s += __shfl_xor(s, 4);  q_ += __shfl_xor(q_, 4);
                s += __shfl_xor(s, 8);  q_ += __shfl_xor(q_, 8);
                if (lr == 0) {
                    int n = wid * 64 + j * 16 + g * 4 + r;
                    atomicAdd(&stats[n], s);
                    atomicAdd(&stats[256 + n], q_);
                }
            }
        __syncthreads();
        // coalesced store via LDS transpose: 1 KB contiguous per wave-instr
#pragma unroll
        for (int z = 0; z < 8; ++z) {
            int row = wid * 16 + z * 2 + (lane >> 5);
            int cg = lane & 31;
            u16x8 val = *(const u16x8*)&H1[row * 256 + ((cg ^ (row & 7))) * 8];
            *(u16x8*)(outB + (size_t)(m0 + row) * 256 + cg * 8) = val;
        }
    } else {
        // MODE 2: head — relu(acc+bo1) dot wo2 -> per-row sum -> f32 out
        float* rowacc = (float*)H1;
        if (tid < 64) rowacc[tid] = 0.f;
        __syncthreads();
        float p[4] = {0.f, 0.f, 0.f, 0.f};
#pragma unroll
        for (int j = 0; j < 4; ++j) {
            int n4 = wid * 64 + j * 16 + g * 4;
#pragma unroll
            for (int r = 0; r < 4; ++r) {
                float b_ = bias1[n4 + r];
                float w_ = aux1[n4 + r];
#pragma unroll
                for (int i = 0; i < 4; ++i) {
                    float v = acc[i][j][r] + b_;
                    v = v > 0.f ? v : 0.f;
                    p[i] += v * w_;
                }
            }
        }
#pragma unroll
        for (int i = 0; i < 4; ++i) {
            p[i] += __shfl_xor(p[i], 16);
            p[i] += __shfl_xor(p[i], 32);
        }
        if (lane < 16) {
#pragma unroll
            for (int i = 0; i < 4; ++i) atomicAdd(&rowacc[i * 16 + lr], p[i]);
        }
        __syncthreads();
        if (tid < 64) {
            int m = m0 + tid;
            int b_ = m / (NV * TT), v_ = (m >> 6) % NV, t_ = m & 63;
            fout[(size_t)(b_ * TT + t_) * NV + v_] = rowacc[tid] + aux2[0];
        }
    }
}

// -------------------- edge2node: incidence sum + BN2 affine --------------------
__global__ __launch_bounds__(256) void edge2node(const u16* __restrict__ h2,
                                                 const float* __restrict__ scsh2,
                                                 u16* __restrict__ n1) {
    int tid = threadIdx.x;
    int row = blockIdx.x * 8 + (tid >> 5);      // node row
    int ch8 = (tid & 31) * 8;
    int t = row & 63;
    int bv = row >> 6;
    int v = bv % NV;
    int b = bv / NV;
    float acc[8] = {0, 0, 0, 0, 0, 0, 0, 0};
#pragma unroll
    for (int i = 0; i < 9; ++i) {
        int s = i + (i >= v ? 1 : 0);
        int e = s * 9 + (v < s ? v : v - 1);
        u16x8 vv = *(const u16x8*)(h2 + ((size_t)((b * NE + e) * TT + t)) * 256 + ch8);
#pragma unroll
        for (int k = 0; k < 8; ++k) acc[k] += bf2f(vv[k]);
    }
    const float inv9 = 1.f / 9.f;
    u16x8 o;
#pragma unroll
    for (int k = 0; k < 8; ++k) {
        int c = ch8 + k;
        o[k] = f2bf(scsh2[c] * (acc[k] * inv9) + scsh2[256 + c]);
    }
    *(u16x8*)(n1 + (size_t)row * 256 + ch8) = o;
}

extern "C" void kernel_launch(void* const* d_in, const int* in_sizes, int n_in,
                              void* d_out, int out_size, void* d_ws, size_t ws_size,
                              hipStream_t stream) {
    const float* x   = (const float*)d_in[0];
    const float* w1a = (const float*)d_in[1];
    const float* b1a = (const float*)d_in[2];
    const float* w1b = (const float*)d_in[3];
    const float* b1b = (const float*)d_in[4];
    const float* g1  = (const float*)d_in[5];
    const float* be1 = (const float*)d_in[6];
    const float* w2a = (const float*)d_in[7];
    const float* b2a = (const float*)d_in[8];
    const float* w2b = (const float*)d_in[9];
    const float* b2b = (const float*)d_in[10];
    const float* g2  = (const float*)d_in[11];
    const float* be2 = (const float*)d_in[12];
    const float* w3a = (const float*)d_in[13];
    const float* b3a = (const float*)d_in[14];
    const float* w3b = (const float*)d_in[15];
    const float* b3b = (const float*)d_in[16];
    const float* g3  = (const float*)d_in[17];
    const float* be3 = (const float*)d_in[18];
    const float* wo1 = (const float*)d_in[19];
    const float* bo1 = (const float*)d_in[20];
    const float* wo2 = (const float*)d_in[21];
    const float* bo2 = (const float*)d_in[22];
    float* out = (float*)d_out;

    char* ws = (char*)d_ws;
    size_t off = 0;
    auto alloc = [&](size_t bytes) {
        void* p = ws + off;
        off = (off + bytes + 255) & ~(size_t)255;
        return p;
    };
    u16* w1bT = (u16*)alloc(256 * 256 * 2);
    u16* w2aT = (u16*)alloc(256 * 512 * 2);
    u16* w2bT = (u16*)alloc(256 * 256 * 2);
    u16* w3aT = (u16*)alloc(256 * 256 * 2);
    u16* w3bT = (u16*)alloc(256 * 256 * 2);
    u16* wo1T = (u16*)alloc(256 * 256 * 2);
    float* sums  = (float*)alloc(3 * 512 * 4);
    float* scsh1 = (float*)alloc(512 * 4);
    float* scsh2 = (float*)alloc(512 * 4);
    float* scsh3 = (float*)alloc(512 * 4);
    float* b2aF  = (float*)alloc(256 * 4);
    u16* S0 = (u16*)alloc((size_t)R1 * 256 * 2);
    u16* S1 = (u16*)alloc((size_t)R1 * 256 * 2);
    u16* S2 = (u16*)alloc((size_t)R1 * 256 * 2);
    u16* BIG2 = (u16*)alloc((size_t)R2 * 256 * 2);

    transpose_w<<<256, 256, 0, stream>>>(w1b, w1bT, 256, 256);
    transpose_w<<<256, 256, 0, stream>>>(w2b, w2bT, 256, 256);
    transpose_w<<<256, 256, 0, stream>>>(w3a, w3aT, 256, 256);
    transpose_w<<<256, 256, 0, stream>>>(w3b, w3bT, 256, 256);
    transpose_w<<<256, 256, 0, stream>>>(wo1, wo1T, 256, 256);
    zero_stats<<<6, 256, 0, stream>>>(sums, 3 * 512);

    // mlp1: fc1 (K=4, computed in staging) + fc2 GEMM + stats epilogue
    mm<2, 0><<<R1 / 64, 256, 0, stream>>>(nullptr, 256, w1bT, b1b, nullptr, nullptr,
                                          x, w1a, b1a, S1, sums, nullptr);
    stats_final<<<1, 256, 0, stream>>>(sums, g1, be1, 1.f / R1, scsh1);
    fold_w2a<<<512, 256, 0, stream>>>(w2a, scsh1, w2aT);
    fold_b2a<<<1, 256, 0, stream>>>(w2a, scsh1, b2a, b2aF);

    // mlp2: gather fc1 (K=512, BN1 folded into weights) + fc2 fused + stats
    mm<1, 1><<<R2 / 64, 256, 0, stream>>>(S1, 512, w2aT, b2aF, w2bT, b2b,
                                          nullptr, nullptr, nullptr, BIG2, sums + 512, nullptr);
    stats_final<<<1, 256, 0, stream>>>(sums + 512, g2, be2, 1.f / R2, scsh2);

    edge2node<<<R1 / 8, 256, 0, stream>>>(BIG2, scsh2, S0);

    // mlp3: fc1+fc2 fused + stats
    mm<0, 1><<<R1 / 64, 256, 0, stream>>>(S0, 256, w3aT, b3a, w3bT, b3b,
                                          nullptr, nullptr, nullptr, S2, sums + 1024, nullptr);
    stats_final<<<1, 256, 0, stream>>>(sums + 1024, g3, be3, 1.f / R1, scsh3);

    // head: affine3+relu staged, wo1 GEMM, relu, dot wo2 -> out
    mm<3, 2><<<R1 / 64, 256, 0, stream>>>(S2, 256, wo1T, bo1, nullptr, nullptr,
                                          scsh3, wo2, bo2, nullptr, nullptr, out);
}